// Round 10
// baseline (243.186 us; speedup 1.0000x reference)
//
#include <hip/hip_runtime.h>
#include <hip/hip_bf16.h>
#include <hip/hip_fp16.h>

#define DIM 128
#define NCHUNK 256  // chunks for 2-level scan
#define WLD 136     // padded LDS row stride (bf16 elems): 272B -> benign aliasing

typedef unsigned short u16;
typedef unsigned int u32;
typedef __attribute__((ext_vector_type(8))) short bf16x8;  // 8 bf16 = 4 VGPRs
typedef __attribute__((ext_vector_type(4))) float f32x4;

__device__ __forceinline__ float bfbits2f(u16 u) {
    return __uint_as_float(((u32)u) << 16);
}
__device__ __forceinline__ u16 f2bf(float f) {
    __hip_bfloat16 b = __float2bfloat16(f);
    return *reinterpret_cast<u16*>(&b);
}
__device__ __forceinline__ u32 pack2bf(float lo, float hi) {
    return (u32)f2bf(lo) | ((u32)f2bf(hi) << 16);
}
__device__ __forceinline__ float h16tof(u16 u) {
    __half hh = *reinterpret_cast<__half*>(&u);
    return __half2float(hh);
}
__device__ __forceinline__ u16 ftoh16(float f) {
    __half hh = __float2half(f);
    return *reinterpret_cast<u16*>(&hh);
}

// dtype probe: treats even u16 words as bf16; f32 mantissa halves look "weird".
__device__ __forceinline__ int probe_flag_serial(const u16* __restrict__ x) {
    int weird = 0;
    for (int i = 0; i < 256; i += 2) {
        u16 v = x[i];
        int e = (v >> 7) & 0xff;
        if ((v & 0x7fff) != 0 && (e >= 133 || e <= 100)) weird++;
    }
    return (weird > 16) ? 1 : 0;
}

// ---- FUSED heterogeneous dispatch: even blocks = layer-1 GEMM tile, odd = count.
// gemm1 (MFMA/L3-bound) and count (atomic write-through-bound, ~600 GB/s random
// 32B ceiling) use disjoint resources -> dur ~= max(44, 15), confirmed 46.7us.
// Count role records each edge's rank (atomicAdd return = free). GEMM output h
// is PANEL-MAJOR: h0,h1 = [N][64] bf16 (one row = one 128B line) so the agg can
// run per-panel with an L2-resident-ish footprint. ----
__global__ __launch_bounds__(256) void k_gemm_count(const void* __restrict__ in,
                                                    const void* __restrict__ W,
                                                    u16* __restrict__ h0,
                                                    u16* __restrict__ h1, int N,
                                                    const int* __restrict__ dst,
                                                    int* __restrict__ counts,
                                                    int* __restrict__ rank, int E,
                                                    int* __restrict__ flagp,
                                                    int gblk, int cblk) {
    const int bid = blockIdx.x;
    const int tid = threadIdx.x;

    if (bid & 1) {
        // ---------------- count role: 1024 edges/block, 4/thread ----------------
        const int cid = bid >> 1;
        if (cid >= cblk) return;
        if (cid == 0 && tid == 0) *flagp = probe_flag_serial((const u16*)in);
        const int base = cid * 1024;
#pragma unroll
        for (int k = 0; k < 4; ++k) {
            int e = base + k * 256 + tid;
            if (e < E) rank[e] = atomicAdd(&counts[dst[e]], 1);
        }
        return;
    }

    // ---------------- gemm role: 64 nodes x 128 cols, K=128 ----------------
    const int gid = bid >> 1;
    if (gid >= gblk) return;

    __shared__ u16 Wsh[128 * WLD];
    __shared__ int flag_sh;
    if (tid == 0) flag_sh = 0;
    __syncthreads();
    if (tid < 128) {
        u16 v = ((const u16*)in)[tid * 2];
        int ex = (v >> 7) & 0xff;
        if ((v & 0x7fff) != 0 && (ex >= 133 || ex <= 100)) atomicAdd(&flag_sh, 1);
    }
    __syncthreads();
    const int flag = (flag_sh > 16) ? 1 : 0;  // layer 1: input dtype follows flag
    const int n0 = gid * 64;

    if (flag) {
        const float* Wf = (const float*)W;
        for (int t = tid; t < 128 * 32; t += 256) {
            int r = t >> 5, c4 = (t & 31) * 4;
            float4 w = *(const float4*)(Wf + r * DIM + c4);
            uint2 pw = make_uint2(pack2bf(w.x, w.y), pack2bf(w.z, w.w));
            *(uint2*)(Wsh + r * WLD + c4) = pw;
        }
    } else {
        const u16* Wu = (const u16*)W;
        for (int t = tid; t < 128 * 16; t += 256) {
            int r = t >> 4, c8 = (t & 15) * 8;
            *(int4*)(Wsh + r * WLD + c8) = *(const int4*)(Wu + r * DIM + c8);
        }
    }

    const int wid = tid >> 6;
    const int lane = tid & 63;
    const int m_base = wid * 16;
    const int idx16 = lane & 15;
    const int koff = (lane >> 4) * 8;
    const int n = n0 + m_base + idx16;

    bf16x8 afrag[4];
    if (flag) {
        const float* xf = (const float*)in;
#pragma unroll
        for (int ks = 0; ks < 4; ++ks) {
            if (n < N) {
                const float* p = xf + (size_t)n * DIM + ks * 32 + koff;
                float4 a = *(const float4*)p;
                float4 b = *(const float4*)(p + 4);
                union { bf16x8 v8; u32 w[4]; } cv;
                cv.w[0] = pack2bf(a.x, a.y);
                cv.w[1] = pack2bf(a.z, a.w);
                cv.w[2] = pack2bf(b.x, b.y);
                cv.w[3] = pack2bf(b.z, b.w);
                afrag[ks] = cv.v8;
            } else {
                afrag[ks] = (bf16x8)0;
            }
        }
    } else {
        const u16* xu = (const u16*)in;
#pragma unroll
        for (int ks = 0; ks < 4; ++ks) {
            afrag[ks] = (n < N) ? *(const bf16x8*)(xu + (size_t)n * DIM + ks * 32 + koff)
                                : (bf16x8)0;
        }
    }
    __syncthreads();  // Wsh ready

    f32x4 acc[8];
#pragma unroll
    for (int ct = 0; ct < 8; ++ct) acc[ct] = (f32x4){0.f, 0.f, 0.f, 0.f};

#pragma unroll
    for (int ct = 0; ct < 8; ++ct) {
#pragma unroll
        for (int ks = 0; ks < 4; ++ks) {
            bf16x8 bfrag = *(const bf16x8*)(Wsh + (ct * 16 + idx16) * WLD + ks * 32 + koff);
            acc[ct] = __builtin_amdgcn_mfma_f32_16x16x32_bf16(afrag[ks], bfrag, acc[ct], 0, 0, 0);
        }
    }

    const int drow = (lane >> 4) * 4;
#pragma unroll
    for (int ct = 0; ct < 8; ++ct) {
        u16* hp = (ct < 4) ? h0 : h1;
        const int pcol = (ct * 16 + idx16) & 63;
#pragma unroll
        for (int r = 0; r < 4; ++r) {
            int row = n0 + m_base + drow + r;
            if (row < N) hp[(size_t)row * 64 + pcol] = f2bf(acc[ct][r]);
        }
    }
}

// ---- chunk sums of (deg+1): +1 is the appended self-loop slot per node ----
__global__ __launch_bounds__(256) void k_chunksum(const int* __restrict__ counts,
                                                  int* __restrict__ chunksum,
                                                  int N, int chunk) {
    __shared__ int r[256];
    int t = threadIdx.x, b = blockIdx.x;
    int idx = b * chunk + t;
    r[t] = (t < chunk && idx < N) ? counts[idx] + 1 : 0;
    __syncthreads();
    for (int off = 128; off > 0; off >>= 1) {
        if (t < off) r[t] += r[t + off];
        __syncthreads();
    }
    if (t == 0) chunksum[b] = r[0];
}

// ---- rowptr + dis + pay. Each block re-scans the 256 chunksums itself. ----
__global__ __launch_bounds__(256) void k_rowptr(const int* __restrict__ counts,
                                                const int* __restrict__ chunksum,
                                                int* __restrict__ rowptr,
                                                float* __restrict__ dis,
                                                u32* __restrict__ pay,
                                                int N, int chunk) {
    __shared__ int scb[256];
    __shared__ int sc[256];
    int t = threadIdx.x, b = blockIdx.x;

    int cs = chunksum[t];
    scb[t] = cs;
    __syncthreads();
    for (int off = 1; off < 256; off <<= 1) {
        int add = (t >= off) ? scb[t - off] : 0;
        __syncthreads();
        scb[t] += add;
        __syncthreads();
    }
    if (b == 0 && t == 0) rowptr[N] = scb[255];   // total rows = E + N
    const int base = (b == 0) ? 0 : scb[b - 1];

    int idx = b * chunk + t;
    int v = (t < chunk && idx < N) ? counts[idx] + 1 : 0;  // row = deg + self
    sc[t] = v;
    __syncthreads();
    for (int off = 1; off < 256; off <<= 1) {
        int add = (t >= off) ? sc[t - off] : 0;
        __syncthreads();
        sc[t] += add;
        __syncthreads();
    }
    if (t < chunk && idx < N) {
        rowptr[idx] = base + sc[t] - v;  // exclusive prefix
        float dv = rsqrtf((float)v);     // rsqrt(deg+1)
        dis[idx] = dv;
        pay[idx] = ((u32)idx << 16) | (u32)ftoh16(dv);
    }
}

// ---- atomic-free fill: edges at rowptr[d]+rank[e]; self-loop at rowptr[d+1]-1 ----
__global__ __launch_bounds__(256) void k_fill(const int* __restrict__ src,
                                              const int* __restrict__ dst,
                                              const int* __restrict__ rowptr,
                                              const int* __restrict__ rank,
                                              const u32* __restrict__ pay,
                                              u32* __restrict__ elist, int E, int N) {
    int e = blockIdx.x * blockDim.x + threadIdx.x;
    if (e < E) {
        elist[rowptr[dst[e]] + rank[e]] = pay[src[e]];
    } else if (e < E + N) {
        int d = e - E;
        elist[rowptr[d + 1] - 1] = pay[d];   // self-loop: weight f16(dis[d])
    }
}

// ---- standalone GEMM for layer 2 (input = bf16 act row-major; panel output) ----
__global__ __launch_bounds__(256) void k_gemm(const void* __restrict__ in,
                                              const void* __restrict__ W,
                                              u16* __restrict__ h0,
                                              u16* __restrict__ h1, int N,
                                              const int* __restrict__ flagp) {
    __shared__ u16 Wsh[128 * WLD];
    const int tid = threadIdx.x;
    const int flag = *flagp;
    const int n0 = blockIdx.x * 64;

    if (flag) {
        const float* Wf = (const float*)W;
        for (int t = tid; t < 128 * 32; t += 256) {
            int r = t >> 5, c4 = (t & 31) * 4;
            float4 w = *(const float4*)(Wf + r * DIM + c4);
            uint2 pw = make_uint2(pack2bf(w.x, w.y), pack2bf(w.z, w.w));
            *(uint2*)(Wsh + r * WLD + c4) = pw;
        }
    } else {
        const u16* Wu = (const u16*)W;
        for (int t = tid; t < 128 * 16; t += 256) {
            int r = t >> 4, c8 = (t & 15) * 8;
            *(int4*)(Wsh + r * WLD + c8) = *(const int4*)(Wu + r * DIM + c8);
        }
    }

    const int wid = tid >> 6;
    const int lane = tid & 63;
    const int m_base = wid * 16;
    const int idx16 = lane & 15;
    const int koff = (lane >> 4) * 8;
    const int n = n0 + m_base + idx16;

    bf16x8 afrag[4];
    const u16* xu = (const u16*)in;
#pragma unroll
    for (int ks = 0; ks < 4; ++ks) {
        afrag[ks] = (n < N) ? *(const bf16x8*)(xu + (size_t)n * DIM + ks * 32 + koff)
                            : (bf16x8)0;
    }
    __syncthreads();  // Wsh ready

    f32x4 acc[8];
#pragma unroll
    for (int ct = 0; ct < 8; ++ct) acc[ct] = (f32x4){0.f, 0.f, 0.f, 0.f};

#pragma unroll
    for (int ct = 0; ct < 8; ++ct) {
#pragma unroll
        for (int ks = 0; ks < 4; ++ks) {
            bf16x8 bfrag = *(const bf16x8*)(Wsh + (ct * 16 + idx16) * WLD + ks * 32 + koff);
            acc[ct] = __builtin_amdgcn_mfma_f32_16x16x32_bf16(afrag[ks], bfrag, acc[ct], 0, 0, 0);
        }
    }

    const int drow = (lane >> 4) * 4;
#pragma unroll
    for (int ct = 0; ct < 8; ++ct) {
        u16* hp = (ct < 4) ? h0 : h1;
        const int pcol = (ct * 16 + idx16) & 63;
#pragma unroll
        for (int r = 0; r < 4; ++r) {
            int row = n0 + m_base + drow + r;
            if (row < N) hp[(size_t)row * 64 + pcol] = f2bf(acc[ct][r]);
        }
    }
}

// ---- fused CSR aggregate, PANEL version: hp = [N][64] bf16 (row = one 128B
// line, 100% utilization). One dispatch touches only ONE 6.4MB panel -> per-XCD
// L2 footprint halves vs row-major (hit 31% -> ~62%, model: FETCH 143 -> ~46MB).
// Wave per dst: lane (sub=L>>3, cb=(L&7)*8): 8 edges/instr, 4-deep MLP = 32
// edges/iter. Clamped slots re-read elist[last]'s row (L1 hit, w=0). Butterfly
// xor 8,16,32 merges; epilogue on sub==0 (8 lanes x 8 cols = 64 cols). ----
template <bool RELU, bool OUT_BF16>
__global__ __launch_bounds__(256) void k_agg(const u16* __restrict__ hp,
                                             const float* __restrict__ dis,
                                             const int* __restrict__ rowptr,
                                             const u32* __restrict__ elist,
                                             const void* __restrict__ bias,
                                             void* __restrict__ out, int N, int co,
                                             const int* __restrict__ flagp) {
    const int lane = threadIdx.x & 63;
    const int d = blockIdx.x * 4 + (threadIdx.x >> 6);
    if (d >= N) return;
    const int flag = *flagp;
    const int sub = lane >> 3;       // edge slot 0..7
    const int cb  = (lane & 7) * 8;  // col base within panel: 8 cols per lane

    const int start = rowptr[d];
    const int end   = rowptr[d + 1];
    const int last  = end - 1;       // end > start always (self-loop)
    const float dd  = dis[d];

    float acc[8];
#pragma unroll
    for (int k = 0; k < 8; ++k) acc[k] = 0.f;

    for (int j = start; j < end; j += 32) {
        const int i0 = j + sub, i1 = i0 + 8, i2 = i0 + 16, i3 = i0 + 24;
        const u32 e0 = elist[i0 <= last ? i0 : last];
        const u32 e1 = elist[i1 <= last ? i1 : last];
        const u32 e2 = elist[i2 <= last ? i2 : last];
        const u32 e3 = elist[i3 <= last ? i3 : last];
        const float w0 = (i0 <= last) ? h16tof((u16)(e0 & 0xffff)) : 0.f;
        const float w1 = (i1 <= last) ? h16tof((u16)(e1 & 0xffff)) : 0.f;
        const float w2 = (i2 <= last) ? h16tof((u16)(e2 & 0xffff)) : 0.f;
        const float w3 = (i3 <= last) ? h16tof((u16)(e3 & 0xffff)) : 0.f;
        const int4 r0 = *(const int4*)(hp + ((size_t)(e0 >> 16)) * 64 + cb);
        const int4 r1 = *(const int4*)(hp + ((size_t)(e1 >> 16)) * 64 + cb);
        const int4 r2 = *(const int4*)(hp + ((size_t)(e2 >> 16)) * 64 + cb);
        const int4 r3 = *(const int4*)(hp + ((size_t)(e3 >> 16)) * 64 + cb);
        const u32 v0[4] = {(u32)r0.x, (u32)r0.y, (u32)r0.z, (u32)r0.w};
        const u32 v1[4] = {(u32)r1.x, (u32)r1.y, (u32)r1.z, (u32)r1.w};
        const u32 v2[4] = {(u32)r2.x, (u32)r2.y, (u32)r2.z, (u32)r2.w};
        const u32 v3[4] = {(u32)r3.x, (u32)r3.y, (u32)r3.z, (u32)r3.w};
#pragma unroll
        for (int k = 0; k < 4; ++k) {
            acc[2 * k]     = fmaf(bfbits2f((u16)(v0[k] & 0xffff)), w0, acc[2 * k]);
            acc[2 * k + 1] = fmaf(bfbits2f((u16)(v0[k] >> 16)),    w0, acc[2 * k + 1]);
        }
#pragma unroll
        for (int k = 0; k < 4; ++k) {
            acc[2 * k]     = fmaf(bfbits2f((u16)(v1[k] & 0xffff)), w1, acc[2 * k]);
            acc[2 * k + 1] = fmaf(bfbits2f((u16)(v1[k] >> 16)),    w1, acc[2 * k + 1]);
        }
#pragma unroll
        for (int k = 0; k < 4; ++k) {
            acc[2 * k]     = fmaf(bfbits2f((u16)(v2[k] & 0xffff)), w2, acc[2 * k]);
            acc[2 * k + 1] = fmaf(bfbits2f((u16)(v2[k] >> 16)),    w2, acc[2 * k + 1]);
        }
#pragma unroll
        for (int k = 0; k < 4; ++k) {
            acc[2 * k]     = fmaf(bfbits2f((u16)(v3[k] & 0xffff)), w3, acc[2 * k]);
            acc[2 * k + 1] = fmaf(bfbits2f((u16)(v3[k] >> 16)),    w3, acc[2 * k + 1]);
        }
    }

    // merge the 8 edge-slot partials (butterfly: all lanes end with full sum)
#pragma unroll
    for (int k = 0; k < 8; ++k) {
        acc[k] += __shfl_xor(acc[k], 8, 64);
        acc[k] += __shfl_xor(acc[k], 16, 64);
        acc[k] += __shfl_xor(acc[k], 32, 64);
    }

    if (sub != 0) return;  // epilogue on slot 0: 8 lanes x 8 cols = 64 cols

    float res[8];
#pragma unroll
    for (int k = 0; k < 8; ++k) res[k] = acc[k] * dd;  // self-loop already summed
    if (flag) {
        const float* bf = (const float*)bias;
#pragma unroll
        for (int k = 0; k < 8; ++k) res[k] += bf[co + cb + k];
    } else {
        const u16* bu = (const u16*)bias;
#pragma unroll
        for (int k = 0; k < 8; ++k) res[k] += bfbits2f(bu[co + cb + k]);
    }
    if (RELU) {
#pragma unroll
        for (int k = 0; k < 8; ++k) res[k] = res[k] > 0.f ? res[k] : 0.01f * res[k];
    }
    if (OUT_BF16) {
        u32 pk[4];
#pragma unroll
        for (int k = 0; k < 4; ++k) pk[k] = pack2bf(res[2 * k], res[2 * k + 1]);
        *(int4*)((u16*)out + (size_t)d * DIM + co + cb) = make_int4(pk[0], pk[1], pk[2], pk[3]);
    } else {
        float* op = (float*)out + (size_t)d * DIM + co + cb;
        *(float4*)op       = make_float4(res[0], res[1], res[2], res[3]);
        *(float4*)(op + 4) = make_float4(res[4], res[5], res[6], res[7]);
    }
}

extern "C" void kernel_launch(void* const* d_in, const int* in_sizes, int n_in,
                              void* d_out, int out_size, void* d_ws, size_t ws_size,
                              hipStream_t stream) {
    const void* x  = d_in[0];             // f32 (probed; flag-adaptive)
    const int*  ei = (const int*)d_in[1];
    // d_in[2] = batch (unused in eval mode)
    const void* W1 = d_in[3];
    const void* b1 = d_in[4];
    const void* W2 = d_in[5];
    const void* b2 = d_in[6];

    const int N = in_sizes[0] / DIM;
    const int E = in_sizes[1] / 2;
    const int* src = ei;
    const int* dst = ei + E;
    const int chunk = (N + NCHUNK - 1) / NCHUNK;

    // ws layout (256B-aligned slices)
    char* ws = (char*)d_ws;
    size_t o = 0;
    int*   flagp    = (int*)(ws + o);   o += 256;
    float* dis      = (float*)(ws + o); o += (((size_t)N * 4 + 255) & ~(size_t)255);
    int*   counts   = (int*)(ws + o);   o += (((size_t)N * 4 + 255) & ~(size_t)255);
    int*   rowptr   = (int*)(ws + o);   o += (((size_t)(N + 1) * 4 + 255) & ~(size_t)255);
    u32*   pay      = (u32*)(ws + o);   o += (((size_t)N * 4 + 255) & ~(size_t)255);
    int*   chunksum = (int*)(ws + o);   o += 1024;
    int*   rank     = (int*)(ws + o);   o += (((size_t)E * 4 + 255) & ~(size_t)255);
    u32*   elist    = (u32*)(ws + o);   o += (((size_t)(E + N) * 4 + 255) & ~(size_t)255);
    u16*   h0       = (u16*)(ws + o);   o += (((size_t)N * 64 * 2 + 255) & ~(size_t)255);
    u16*   h1       = (u16*)(ws + o);   o += (((size_t)N * 64 * 2 + 255) & ~(size_t)255);

    const int gblk = (N + 63) / 64;
    const int cblk = (E + 1023) / 1024;
    const int fused_nb = 2 * (gblk > cblk ? gblk : cblk);
    const int fblk = (E + N + 255) / 256;
    const int ablk = (N + 3) / 4;

    // layer-1 activations (bf16, row-major) live in d_out's first 12.8 MB;
    // consumed by gemm2 BEFORE the final f32 aggregate overwrites d_out.
    u16* act = (u16*)d_out;

    hipMemsetAsync(counts, 0, (size_t)N * 4, stream);
    // fused: gemm1 (even blocks) || count+rank+probe (odd blocks)
    k_gemm_count<<<fused_nb, 256, 0, stream>>>(x, W1, h0, h1, N, dst, counts, rank, E,
                                               flagp, gblk, cblk);
    k_chunksum<<<NCHUNK, 256, 0, stream>>>(counts, chunksum, N, chunk);
    k_rowptr<<<NCHUNK, 256, 0, stream>>>(counts, chunksum, rowptr, dis, pay, N, chunk);
    k_fill<<<fblk, 256, 0, stream>>>(src, dst, rowptr, rank, pay, elist, E, N);

    // ---- layer 1 aggregate: one panel per dispatch (temporal L2 footprint split) ----
    k_agg<true, true><<<ablk, 256, 0, stream>>>(h0, dis, rowptr, elist, b1, act, N, 0, flagp);
    k_agg<true, true><<<ablk, 256, 0, stream>>>(h1, dis, rowptr, elist, b1, act, N, 64, flagp);

    // ---- layer 2 ----
    k_gemm<<<gblk, 256, 0, stream>>>(act, W2, h0, h1, N, flagp);
    k_agg<false, false><<<ablk, 256, 0, stream>>>(h0, dis, rowptr, elist, b2, d_out, N, 0, flagp);
    k_agg<false, false><<<ablk, 256, 0, stream>>>(h1, dis, rowptr, elist, b2, d_out, N, 64, flagp);
}

// Round 11
// 239.571 us; speedup vs baseline: 1.0151x; 1.0151x over previous
//
#include <hip/hip_runtime.h>
#include <hip/hip_bf16.h>
#include <hip/hip_fp16.h>

#define DIM 128
#define NCHUNK 256  // chunks for the scan
#define WLD 136     // padded LDS row stride (bf16 elems): 272B -> benign aliasing

typedef unsigned short u16;
typedef unsigned int u32;
typedef __attribute__((ext_vector_type(8))) short bf16x8;  // 8 bf16 = 4 VGPRs
typedef __attribute__((ext_vector_type(4))) float f32x4;

__device__ __forceinline__ float bfbits2f(u16 u) {
    return __uint_as_float(((u32)u) << 16);
}
__device__ __forceinline__ u16 f2bf(float f) {
    __hip_bfloat16 b = __float2bfloat16(f);
    return *reinterpret_cast<u16*>(&b);
}
__device__ __forceinline__ u32 pack2bf(float lo, float hi) {
    return (u32)f2bf(lo) | ((u32)f2bf(hi) << 16);
}
__device__ __forceinline__ float h16tof(u16 u) {
    __half hh = *reinterpret_cast<__half*>(&u);
    return __half2float(hh);
}
__device__ __forceinline__ u16 ftoh16(float f) {
    __half hh = __float2half(f);
    return *reinterpret_cast<u16*>(&hh);
}

// dtype probe: treats even u16 words as bf16; f32 mantissa halves look "weird".
__device__ __forceinline__ int probe_flag_serial(const u16* __restrict__ x) {
    int weird = 0;
    for (int i = 0; i < 256; i += 2) {
        u16 v = x[i];
        int e = (v >> 7) & 0xff;
        if ((v & 0x7fff) != 0 && (e >= 133 || e <= 100)) weird++;
    }
    return (weird > 16) ? 1 : 0;
}

// ---- FUSED heterogeneous dispatch: even blocks = layer-1 GEMM tile, odd = count.
// gemm1 (MFMA/L3-bound) and count (atomic write-through-bound, ~600 GB/s random
// 32B ceiling) use disjoint resources -> dur ~= max(44, 15), confirmed 46.7us.
// Count role records each edge's rank (atomicAdd return = free). ----
__global__ __launch_bounds__(256) void k_gemm_count(const void* __restrict__ in,
                                                    const void* __restrict__ W,
                                                    u16* __restrict__ h, int N,
                                                    const int* __restrict__ dst,
                                                    int* __restrict__ counts,
                                                    int* __restrict__ rank, int E,
                                                    int* __restrict__ flagp,
                                                    int gblk, int cblk) {
    const int bid = blockIdx.x;
    const int tid = threadIdx.x;

    if (bid & 1) {
        // ---------------- count role: 1024 edges/block, 4/thread ----------------
        const int cid = bid >> 1;
        if (cid >= cblk) return;
        if (cid == 0 && tid == 0) *flagp = probe_flag_serial((const u16*)in);
        const int base = cid * 1024;
#pragma unroll
        for (int k = 0; k < 4; ++k) {
            int e = base + k * 256 + tid;
            if (e < E) rank[e] = atomicAdd(&counts[dst[e]], 1);
        }
        return;
    }

    // ---------------- gemm role: 64 nodes x 128 cols, K=128 ----------------
    const int gid = bid >> 1;
    if (gid >= gblk) return;

    __shared__ u16 Wsh[128 * WLD];
    __shared__ int flag_sh;
    if (tid == 0) flag_sh = 0;
    __syncthreads();
    if (tid < 128) {
        u16 v = ((const u16*)in)[tid * 2];
        int ex = (v >> 7) & 0xff;
        if ((v & 0x7fff) != 0 && (ex >= 133 || ex <= 100)) atomicAdd(&flag_sh, 1);
    }
    __syncthreads();
    const int flag = (flag_sh > 16) ? 1 : 0;  // layer 1: input dtype follows flag
    const int n0 = gid * 64;

    if (flag) {
        const float* Wf = (const float*)W;
        for (int t = tid; t < 128 * 32; t += 256) {
            int r = t >> 5, c4 = (t & 31) * 4;
            float4 w = *(const float4*)(Wf + r * DIM + c4);
            uint2 pw = make_uint2(pack2bf(w.x, w.y), pack2bf(w.z, w.w));
            *(uint2*)(Wsh + r * WLD + c4) = pw;
        }
    } else {
        const u16* Wu = (const u16*)W;
        for (int t = tid; t < 128 * 16; t += 256) {
            int r = t >> 4, c8 = (t & 15) * 8;
            *(int4*)(Wsh + r * WLD + c8) = *(const int4*)(Wu + r * DIM + c8);
        }
    }

    const int wid = tid >> 6;
    const int lane = tid & 63;
    const int m_base = wid * 16;
    const int idx16 = lane & 15;
    const int koff = (lane >> 4) * 8;
    const int n = n0 + m_base + idx16;

    bf16x8 afrag[4];
    if (flag) {
        const float* xf = (const float*)in;
#pragma unroll
        for (int ks = 0; ks < 4; ++ks) {
            if (n < N) {
                const float* p = xf + (size_t)n * DIM + ks * 32 + koff;
                float4 a = *(const float4*)p;
                float4 b = *(const float4*)(p + 4);
                union { bf16x8 v8; u32 w[4]; } cv;
                cv.w[0] = pack2bf(a.x, a.y);
                cv.w[1] = pack2bf(a.z, a.w);
                cv.w[2] = pack2bf(b.x, b.y);
                cv.w[3] = pack2bf(b.z, b.w);
                afrag[ks] = cv.v8;
            } else {
                afrag[ks] = (bf16x8)0;
            }
        }
    } else {
        const u16* xu = (const u16*)in;
#pragma unroll
        for (int ks = 0; ks < 4; ++ks) {
            afrag[ks] = (n < N) ? *(const bf16x8*)(xu + (size_t)n * DIM + ks * 32 + koff)
                                : (bf16x8)0;
        }
    }
    __syncthreads();  // Wsh ready

    f32x4 acc[8];
#pragma unroll
    for (int ct = 0; ct < 8; ++ct) acc[ct] = (f32x4){0.f, 0.f, 0.f, 0.f};

#pragma unroll
    for (int ct = 0; ct < 8; ++ct) {
#pragma unroll
        for (int ks = 0; ks < 4; ++ks) {
            bf16x8 bfrag = *(const bf16x8*)(Wsh + (ct * 16 + idx16) * WLD + ks * 32 + koff);
            acc[ct] = __builtin_amdgcn_mfma_f32_16x16x32_bf16(afrag[ks], bfrag, acc[ct], 0, 0, 0);
        }
    }

    const int drow = (lane >> 4) * 4;
#pragma unroll
    for (int ct = 0; ct < 8; ++ct) {
#pragma unroll
        for (int r = 0; r < 4; ++r) {
            int row = n0 + m_base + drow + r;
            if (row < N) h[(size_t)row * DIM + ct * 16 + idx16] = f2bf(acc[ct][r]);
        }
    }
}

// ---- rowptr + dis + pay, self-basing (k_chunksum dispatch eliminated).
// Block b derives its base by directly reducing counts[0 .. b*chunk) -- 25MB
// aggregate of L2-resident coalesced reads across the grid (~1us) in place of
// a separate dispatch + launch gap + chunksum round-trip. Row size = deg+1
// (appended self-loop slot). ----
__global__ __launch_bounds__(256) void k_rowptr(const int* __restrict__ counts,
                                                int* __restrict__ rowptr,
                                                float* __restrict__ dis,
                                                u32* __restrict__ pay,
                                                int N, int chunk) {
    __shared__ int red[256];
    __shared__ int sc[256];
    int t = threadIdx.x, b = blockIdx.x;

    // phase 1: base = sum_{i<lo} (counts[i]+1), lo = min(b*chunk, N)
    const int lim = b * chunk;
    const int lo = lim < N ? lim : N;
    int part = 0;
    for (int i = t; i < lo; i += 256) part += counts[i];
    red[t] = part;
    __syncthreads();
    for (int off = 128; off > 0; off >>= 1) {
        if (t < off) red[t] += red[t + off];
        __syncthreads();
    }
    const int base = red[0] + lo;   // +1 self-loop per node below

    // phase 2: per-node inclusive scan within this chunk
    int idx = lim + t;
    int v = (t < chunk && idx < N) ? counts[idx] + 1 : 0;  // row = deg + self
    sc[t] = v;
    __syncthreads();
    for (int off = 1; off < 256; off <<= 1) {
        int add = (t >= off) ? sc[t - off] : 0;
        __syncthreads();
        sc[t] += add;
        __syncthreads();
    }
    if (t < chunk && idx < N) {
        rowptr[idx] = base + sc[t] - v;  // exclusive prefix
        float dv = rsqrtf((float)v);     // rsqrt(deg+1)
        dis[idx] = dv;
        pay[idx] = ((u32)idx << 16) | (u32)ftoh16(dv);
        if (idx == N - 1) rowptr[N] = base + sc[t];  // total = E + N
    }
}

// ---- atomic-free fill: edges at rowptr[d]+rank[e]; self-loop at rowptr[d+1]-1 ----
__global__ __launch_bounds__(256) void k_fill(const int* __restrict__ src,
                                              const int* __restrict__ dst,
                                              const int* __restrict__ rowptr,
                                              const int* __restrict__ rank,
                                              const u32* __restrict__ pay,
                                              u32* __restrict__ elist, int E, int N) {
    int e = blockIdx.x * blockDim.x + threadIdx.x;
    if (e < E) {
        elist[rowptr[dst[e]] + rank[e]] = pay[src[e]];
    } else if (e < E + N) {
        int d = e - E;
        elist[rowptr[d + 1] - 1] = pay[d];   // self-loop: weight f16(dis[d])
    }
}

// ---- standalone GEMM for layer 2 (input always bf16 act; W dtype via flagp) ----
__global__ __launch_bounds__(256) void k_gemm(const void* __restrict__ in,
                                              const void* __restrict__ W,
                                              u16* __restrict__ h, int N,
                                              const int* __restrict__ flagp) {
    __shared__ u16 Wsh[128 * WLD];
    const int tid = threadIdx.x;
    const int flag = *flagp;
    const int n0 = blockIdx.x * 64;

    if (flag) {
        const float* Wf = (const float*)W;
        for (int t = tid; t < 128 * 32; t += 256) {
            int r = t >> 5, c4 = (t & 31) * 4;
            float4 w = *(const float4*)(Wf + r * DIM + c4);
            uint2 pw = make_uint2(pack2bf(w.x, w.y), pack2bf(w.z, w.w));
            *(uint2*)(Wsh + r * WLD + c4) = pw;
        }
    } else {
        const u16* Wu = (const u16*)W;
        for (int t = tid; t < 128 * 16; t += 256) {
            int r = t >> 4, c8 = (t & 15) * 8;
            *(int4*)(Wsh + r * WLD + c8) = *(const int4*)(Wu + r * DIM + c8);
        }
    }

    const int wid = tid >> 6;
    const int lane = tid & 63;
    const int m_base = wid * 16;
    const int idx16 = lane & 15;
    const int koff = (lane >> 4) * 8;
    const int n = n0 + m_base + idx16;

    bf16x8 afrag[4];
    const u16* xu = (const u16*)in;
#pragma unroll
    for (int ks = 0; ks < 4; ++ks) {
        afrag[ks] = (n < N) ? *(const bf16x8*)(xu + (size_t)n * DIM + ks * 32 + koff)
                            : (bf16x8)0;
    }
    __syncthreads();  // Wsh ready

    f32x4 acc[8];
#pragma unroll
    for (int ct = 0; ct < 8; ++ct) acc[ct] = (f32x4){0.f, 0.f, 0.f, 0.f};

#pragma unroll
    for (int ct = 0; ct < 8; ++ct) {
#pragma unroll
        for (int ks = 0; ks < 4; ++ks) {
            bf16x8 bfrag = *(const bf16x8*)(Wsh + (ct * 16 + idx16) * WLD + ks * 32 + koff);
            acc[ct] = __builtin_amdgcn_mfma_f32_16x16x32_bf16(afrag[ks], bfrag, acc[ct], 0, 0, 0);
        }
    }

    const int drow = (lane >> 4) * 4;
#pragma unroll
    for (int ct = 0; ct < 8; ++ct) {
#pragma unroll
        for (int r = 0; r < 4; ++r) {
            int row = n0 + m_base + drow + r;
            if (row < N) h[(size_t)row * DIM + ct * 16 + idx16] = f2bf(acc[ct][r]);
        }
    }
}

// ---- fused CSR aggregate (round-8 structure, best measured): one wave per dst.
// Self-loop lives IN elist (row len = deg+1, always >=1). 16 edges/iter, 4
// independent dwordx4 gathers in flight per lane; each instr covers 4 edges x
// 256B row = 1KB wave-wide, 100% line use. Clamped slots (w=0) re-read
// elist[last]'s row (L1 broadcast hit). Butterfly xor 16,32 merges quarters.
// NOTE (r9/r10 lesson): agg is per-CU MSHR x LLC-latency bound (~3.1 TB/s
// beyond-L2); footprint reshuffles (panels/chunks/XCD-pins) don't help because
// total line count is invariant. Do not re-attempt locality schemes here. ----
template <bool RELU, bool OUT_BF16>
__global__ __launch_bounds__(256) void k_agg(const u16* __restrict__ h,
                                             const float* __restrict__ dis,
                                             const int* __restrict__ rowptr,
                                             const u32* __restrict__ elist,
                                             const void* __restrict__ bias,
                                             void* __restrict__ out, int N,
                                             const int* __restrict__ flagp) {
    const int lane = threadIdx.x & 63;
    const int d = blockIdx.x * 4 + (threadIdx.x >> 6);
    if (d >= N) return;
    const int flag = *flagp;
    const int q  = lane >> 4;        // quarter id -> edge residue class (mod 4)
    const int cb = (lane & 15) * 8;  // col base: 8 cols per lane

    const int start = rowptr[d];
    const int end   = rowptr[d + 1];
    const int last  = end - 1;       // end > start always (self-loop)
    const float dd  = dis[d];

    float acc[8];
#pragma unroll
    for (int k = 0; k < 8; ++k) acc[k] = 0.f;

    for (int j = start; j < end; j += 16) {
        const int i0 = j + q, i1 = i0 + 4, i2 = i0 + 8, i3 = i0 + 12;
        const u32 e0 = elist[i0 <= last ? i0 : last];
        const u32 e1 = elist[i1 <= last ? i1 : last];
        const u32 e2 = elist[i2 <= last ? i2 : last];
        const u32 e3 = elist[i3 <= last ? i3 : last];
        const float w0 = (i0 <= last) ? h16tof((u16)(e0 & 0xffff)) : 0.f;
        const float w1 = (i1 <= last) ? h16tof((u16)(e1 & 0xffff)) : 0.f;
        const float w2 = (i2 <= last) ? h16tof((u16)(e2 & 0xffff)) : 0.f;
        const float w3 = (i3 <= last) ? h16tof((u16)(e3 & 0xffff)) : 0.f;
        const int4 r0 = *(const int4*)(h + ((size_t)(e0 >> 16)) * DIM + cb);
        const int4 r1 = *(const int4*)(h + ((size_t)(e1 >> 16)) * DIM + cb);
        const int4 r2 = *(const int4*)(h + ((size_t)(e2 >> 16)) * DIM + cb);
        const int4 r3 = *(const int4*)(h + ((size_t)(e3 >> 16)) * DIM + cb);
        const u32 v0[4] = {(u32)r0.x, (u32)r0.y, (u32)r0.z, (u32)r0.w};
        const u32 v1[4] = {(u32)r1.x, (u32)r1.y, (u32)r1.z, (u32)r1.w};
        const u32 v2[4] = {(u32)r2.x, (u32)r2.y, (u32)r2.z, (u32)r2.w};
        const u32 v3[4] = {(u32)r3.x, (u32)r3.y, (u32)r3.z, (u32)r3.w};
#pragma unroll
        for (int k = 0; k < 4; ++k) {
            acc[2 * k]     = fmaf(bfbits2f((u16)(v0[k] & 0xffff)), w0, acc[2 * k]);
            acc[2 * k + 1] = fmaf(bfbits2f((u16)(v0[k] >> 16)),    w0, acc[2 * k + 1]);
        }
#pragma unroll
        for (int k = 0; k < 4; ++k) {
            acc[2 * k]     = fmaf(bfbits2f((u16)(v1[k] & 0xffff)), w1, acc[2 * k]);
            acc[2 * k + 1] = fmaf(bfbits2f((u16)(v1[k] >> 16)),    w1, acc[2 * k + 1]);
        }
#pragma unroll
        for (int k = 0; k < 4; ++k) {
            acc[2 * k]     = fmaf(bfbits2f((u16)(v2[k] & 0xffff)), w2, acc[2 * k]);
            acc[2 * k + 1] = fmaf(bfbits2f((u16)(v2[k] >> 16)),    w2, acc[2 * k + 1]);
        }
#pragma unroll
        for (int k = 0; k < 4; ++k) {
            acc[2 * k]     = fmaf(bfbits2f((u16)(v3[k] & 0xffff)), w3, acc[2 * k]);
            acc[2 * k + 1] = fmaf(bfbits2f((u16)(v3[k] >> 16)),    w3, acc[2 * k + 1]);
        }
    }

#pragma unroll
    for (int k = 0; k < 8; ++k) {
        acc[k] += __shfl_xor(acc[k], 16, 64);
        acc[k] += __shfl_xor(acc[k], 32, 64);
    }

    if (q != 0) return;  // epilogue on quarter 0: 16 lanes x 8 cols = 128 cols

    float res[8];
#pragma unroll
    for (int k = 0; k < 8; ++k) res[k] = acc[k] * dd;  // self-loop already summed
    if (flag) {
        const float* bf = (const float*)bias;
#pragma unroll
        for (int k = 0; k < 8; ++k) res[k] += bf[cb + k];
    } else {
        const u16* bu = (const u16*)bias;
#pragma unroll
        for (int k = 0; k < 8; ++k) res[k] += bfbits2f(bu[cb + k]);
    }
    if (RELU) {
#pragma unroll
        for (int k = 0; k < 8; ++k) res[k] = res[k] > 0.f ? res[k] : 0.01f * res[k];
    }
    if (OUT_BF16) {
        u32 pk[4];
#pragma unroll
        for (int k = 0; k < 4; ++k) pk[k] = pack2bf(res[2 * k], res[2 * k + 1]);
        *(int4*)((u16*)out + (size_t)d * DIM + cb) = make_int4(pk[0], pk[1], pk[2], pk[3]);
    } else {
        float* op = (float*)out + (size_t)d * DIM + cb;
        *(float4*)op       = make_float4(res[0], res[1], res[2], res[3]);
        *(float4*)(op + 4) = make_float4(res[4], res[5], res[6], res[7]);
    }
}

extern "C" void kernel_launch(void* const* d_in, const int* in_sizes, int n_in,
                              void* d_out, int out_size, void* d_ws, size_t ws_size,
                              hipStream_t stream) {
    const void* x  = d_in[0];             // f32 (probed; flag-adaptive)
    const int*  ei = (const int*)d_in[1];
    // d_in[2] = batch (unused in eval mode)
    const void* W1 = d_in[3];
    const void* b1 = d_in[4];
    const void* W2 = d_in[5];
    const void* b2 = d_in[6];

    const int N = in_sizes[0] / DIM;
    const int E = in_sizes[1] / 2;
    const int* src = ei;
    const int* dst = ei + E;
    const int chunk = (N + NCHUNK - 1) / NCHUNK;

    // ws layout (256B-aligned slices)
    char* ws = (char*)d_ws;
    size_t o = 0;
    int*   flagp    = (int*)(ws + o);   o += 256;
    float* dis      = (float*)(ws + o); o += (((size_t)N * 4 + 255) & ~(size_t)255);
    int*   counts   = (int*)(ws + o);   o += (((size_t)N * 4 + 255) & ~(size_t)255);
    int*   rowptr   = (int*)(ws + o);   o += (((size_t)(N + 1) * 4 + 255) & ~(size_t)255);
    u32*   pay      = (u32*)(ws + o);   o += (((size_t)N * 4 + 255) & ~(size_t)255);
    int*   rank     = (int*)(ws + o);   o += (((size_t)E * 4 + 255) & ~(size_t)255);
    u32*   elist    = (u32*)(ws + o);   o += (((size_t)(E + N) * 4 + 255) & ~(size_t)255);
    u16*   h        = (u16*)(ws + o);   // N*128 bf16 = 12.8 MB

    const int gblk = (N + 63) / 64;
    const int cblk = (E + 1023) / 1024;
    const int fused_nb = 2 * (gblk > cblk ? gblk : cblk);
    const int fblk = (E + N + 255) / 256;
    const int ablk = (N + 3) / 4;

    // layer-1 activations (bf16, row-major) live in d_out's first 12.8 MB;
    // consumed by gemm2 BEFORE the final f32 aggregate overwrites d_out.
    u16* act = (u16*)d_out;

    hipMemsetAsync(counts, 0, (size_t)N * 4, stream);
    // fused: gemm1 (even blocks) || count+rank+probe (odd blocks)
    k_gemm_count<<<fused_nb, 256, 0, stream>>>(x, W1, h, N, dst, counts, rank, E,
                                               flagp, gblk, cblk);
    k_rowptr<<<NCHUNK, 256, 0, stream>>>(counts, rowptr, dis, pay, N, chunk);
    k_fill<<<fblk, 256, 0, stream>>>(src, dst, rowptr, rank, pay, elist, E, N);

    // ---- layer 1 aggregate ----
    k_agg<true, true><<<ablk, 256, 0, stream>>>(h, dis, rowptr, elist, b1, act, N, flagp);

    // ---- layer 2 ----
    k_gemm<<<gblk, 256, 0, stream>>>(act, W2, h, N, flagp);
    k_agg<false, false><<<ablk, 256, 0, stream>>>(h, dis, rowptr, elist, b2, d_out, N, flagp);
}

// Round 12
// 217.171 us; speedup vs baseline: 1.1198x; 1.1031x over previous
//
#include <hip/hip_runtime.h>
#include <hip/hip_bf16.h>
#include <hip/hip_fp16.h>

#define DIM 128
#define NCHUNK 256  // chunks for 2-level scan
#define WLD 136     // padded LDS row stride (bf16 elems): 272B -> benign aliasing

typedef unsigned short u16;
typedef unsigned int u32;
typedef __attribute__((ext_vector_type(8))) short bf16x8;  // 8 bf16 = 4 VGPRs
typedef __attribute__((ext_vector_type(4))) float f32x4;

__device__ __forceinline__ float bfbits2f(u16 u) {
    return __uint_as_float(((u32)u) << 16);
}
__device__ __forceinline__ u16 f2bf(float f) {
    __hip_bfloat16 b = __float2bfloat16(f);
    return *reinterpret_cast<u16*>(&b);
}
__device__ __forceinline__ u32 pack2bf(float lo, float hi) {
    return (u32)f2bf(lo) | ((u32)f2bf(hi) << 16);
}
__device__ __forceinline__ float h16tof(u16 u) {
    __half hh = *reinterpret_cast<__half*>(&u);
    return __half2float(hh);
}
__device__ __forceinline__ u16 ftoh16(float f) {
    __half hh = __float2half(f);
    return *reinterpret_cast<u16*>(&hh);
}

// dtype probe: treats even u16 words as bf16; f32 mantissa halves look "weird".
__device__ __forceinline__ int probe_flag_serial(const u16* __restrict__ x) {
    int weird = 0;
    for (int i = 0; i < 256; i += 2) {
        u16 v = x[i];
        int e = (v >> 7) & 0xff;
        if ((v & 0x7fff) != 0 && (e >= 133 || e <= 100)) weird++;
    }
    return (weird > 16) ? 1 : 0;
}

// ---- FUSED heterogeneous dispatch: even blocks = layer-1 GEMM tile, odd = count.
// gemm1 (MFMA/L3-bound) and count (atomic write-through-bound, ~600 GB/s random
// 32B ceiling) use disjoint resources -> dur ~= max(44, 15), confirmed 46.7us.
// Count role records each edge's rank (atomicAdd return = free). ----
__global__ __launch_bounds__(256) void k_gemm_count(const void* __restrict__ in,
                                                    const void* __restrict__ W,
                                                    u16* __restrict__ h, int N,
                                                    const int* __restrict__ dst,
                                                    int* __restrict__ counts,
                                                    int* __restrict__ rank, int E,
                                                    int* __restrict__ flagp,
                                                    int gblk, int cblk) {
    const int bid = blockIdx.x;
    const int tid = threadIdx.x;

    if (bid & 1) {
        // ---------------- count role: 1024 edges/block, 4/thread ----------------
        const int cid = bid >> 1;
        if (cid >= cblk) return;
        if (cid == 0 && tid == 0) *flagp = probe_flag_serial((const u16*)in);
        const int base = cid * 1024;
#pragma unroll
        for (int k = 0; k < 4; ++k) {
            int e = base + k * 256 + tid;
            if (e < E) rank[e] = atomicAdd(&counts[dst[e]], 1);
        }
        return;
    }

    // ---------------- gemm role: 64 nodes x 128 cols, K=128 ----------------
    const int gid = bid >> 1;
    if (gid >= gblk) return;

    __shared__ u16 Wsh[128 * WLD];
    __shared__ int flag_sh;
    if (tid == 0) flag_sh = 0;
    __syncthreads();
    if (tid < 128) {
        u16 v = ((const u16*)in)[tid * 2];
        int ex = (v >> 7) & 0xff;
        if ((v & 0x7fff) != 0 && (ex >= 133 || ex <= 100)) atomicAdd(&flag_sh, 1);
    }
    __syncthreads();
    const int flag = (flag_sh > 16) ? 1 : 0;  // layer 1: input dtype follows flag
    const int n0 = gid * 64;

    if (flag) {
        const float* Wf = (const float*)W;
        for (int t = tid; t < 128 * 32; t += 256) {
            int r = t >> 5, c4 = (t & 31) * 4;
            float4 w = *(const float4*)(Wf + r * DIM + c4);
            uint2 pw = make_uint2(pack2bf(w.x, w.y), pack2bf(w.z, w.w));
            *(uint2*)(Wsh + r * WLD + c4) = pw;
        }
    } else {
        const u16* Wu = (const u16*)W;
        for (int t = tid; t < 128 * 16; t += 256) {
            int r = t >> 4, c8 = (t & 15) * 8;
            *(int4*)(Wsh + r * WLD + c8) = *(const int4*)(Wu + r * DIM + c8);
        }
    }

    const int wid = tid >> 6;
    const int lane = tid & 63;
    const int m_base = wid * 16;
    const int idx16 = lane & 15;
    const int koff = (lane >> 4) * 8;
    const int n = n0 + m_base + idx16;

    bf16x8 afrag[4];
    if (flag) {
        const float* xf = (const float*)in;
#pragma unroll
        for (int ks = 0; ks < 4; ++ks) {
            if (n < N) {
                const float* p = xf + (size_t)n * DIM + ks * 32 + koff;
                float4 a = *(const float4*)p;
                float4 b = *(const float4*)(p + 4);
                union { bf16x8 v8; u32 w[4]; } cv;
                cv.w[0] = pack2bf(a.x, a.y);
                cv.w[1] = pack2bf(a.z, a.w);
                cv.w[2] = pack2bf(b.x, b.y);
                cv.w[3] = pack2bf(b.z, b.w);
                afrag[ks] = cv.v8;
            } else {
                afrag[ks] = (bf16x8)0;
            }
        }
    } else {
        const u16* xu = (const u16*)in;
#pragma unroll
        for (int ks = 0; ks < 4; ++ks) {
            afrag[ks] = (n < N) ? *(const bf16x8*)(xu + (size_t)n * DIM + ks * 32 + koff)
                                : (bf16x8)0;
        }
    }
    __syncthreads();  // Wsh ready

    f32x4 acc[8];
#pragma unroll
    for (int ct = 0; ct < 8; ++ct) acc[ct] = (f32x4){0.f, 0.f, 0.f, 0.f};

#pragma unroll
    for (int ct = 0; ct < 8; ++ct) {
#pragma unroll
        for (int ks = 0; ks < 4; ++ks) {
            bf16x8 bfrag = *(const bf16x8*)(Wsh + (ct * 16 + idx16) * WLD + ks * 32 + koff);
            acc[ct] = __builtin_amdgcn_mfma_f32_16x16x32_bf16(afrag[ks], bfrag, acc[ct], 0, 0, 0);
        }
    }

    const int drow = (lane >> 4) * 4;
#pragma unroll
    for (int ct = 0; ct < 8; ++ct) {
#pragma unroll
        for (int r = 0; r < 4; ++r) {
            int row = n0 + m_base + drow + r;
            if (row < N) h[(size_t)row * DIM + ct * 16 + idx16] = f2bf(acc[ct][r]);
        }
    }
}

// ---- chunk sums of (deg+1): +1 is the appended self-loop slot per node.
// NOTE (r11 lesson): folding this into k_rowptr as a per-block re-reduction of
// counts[0..b*chunk) costs ~+19us (block-255 serial L2 tail, 1 block/CU, no
// TLP) -- a separate 256-wide tree dispatch is cheaper than the "saved" launch. ----
__global__ __launch_bounds__(256) void k_chunksum(const int* __restrict__ counts,
                                                  int* __restrict__ chunksum,
                                                  int N, int chunk) {
    __shared__ int r[256];
    int t = threadIdx.x, b = blockIdx.x;
    int idx = b * chunk + t;
    r[t] = (t < chunk && idx < N) ? counts[idx] + 1 : 0;
    __syncthreads();
    for (int off = 128; off > 0; off >>= 1) {
        if (t < off) r[t] += r[t + off];
        __syncthreads();
    }
    if (t == 0) chunksum[b] = r[0];
}

// ---- rowptr + dis + pay. Each block re-scans the 256 chunksums itself. ----
__global__ __launch_bounds__(256) void k_rowptr(const int* __restrict__ counts,
                                                const int* __restrict__ chunksum,
                                                int* __restrict__ rowptr,
                                                float* __restrict__ dis,
                                                u32* __restrict__ pay,
                                                int N, int chunk) {
    __shared__ int scb[256];
    __shared__ int sc[256];
    int t = threadIdx.x, b = blockIdx.x;

    int cs = chunksum[t];
    scb[t] = cs;
    __syncthreads();
    for (int off = 1; off < 256; off <<= 1) {
        int add = (t >= off) ? scb[t - off] : 0;
        __syncthreads();
        scb[t] += add;
        __syncthreads();
    }
    if (b == 0 && t == 0) rowptr[N] = scb[255];   // total rows = E + N
    const int base = (b == 0) ? 0 : scb[b - 1];

    int idx = b * chunk + t;
    int v = (t < chunk && idx < N) ? counts[idx] + 1 : 0;  // row = deg + self
    sc[t] = v;
    __syncthreads();
    for (int off = 1; off < 256; off <<= 1) {
        int add = (t >= off) ? sc[t - off] : 0;
        __syncthreads();
        sc[t] += add;
        __syncthreads();
    }
    if (t < chunk && idx < N) {
        rowptr[idx] = base + sc[t] - v;  // exclusive prefix
        float dv = rsqrtf((float)v);     // rsqrt(deg+1)
        dis[idx] = dv;
        pay[idx] = ((u32)idx << 16) | (u32)ftoh16(dv);
    }
}

// ---- atomic-free fill: edges at rowptr[d]+rank[e]; self-loop at rowptr[d+1]-1 ----
__global__ __launch_bounds__(256) void k_fill(const int* __restrict__ src,
                                              const int* __restrict__ dst,
                                              const int* __restrict__ rowptr,
                                              const int* __restrict__ rank,
                                              const u32* __restrict__ pay,
                                              u32* __restrict__ elist, int E, int N) {
    int e = blockIdx.x * blockDim.x + threadIdx.x;
    if (e < E) {
        elist[rowptr[dst[e]] + rank[e]] = pay[src[e]];
    } else if (e < E + N) {
        int d = e - E;
        elist[rowptr[d + 1] - 1] = pay[d];   // self-loop: weight f16(dis[d])
    }
}

// ---- standalone GEMM for layer 2 (input always bf16 act; W dtype via flagp) ----
__global__ __launch_bounds__(256) void k_gemm(const void* __restrict__ in,
                                              const void* __restrict__ W,
                                              u16* __restrict__ h, int N,
                                              const int* __restrict__ flagp) {
    __shared__ u16 Wsh[128 * WLD];
    const int tid = threadIdx.x;
    const int flag = *flagp;
    const int n0 = blockIdx.x * 64;

    if (flag) {
        const float* Wf = (const float*)W;
        for (int t = tid; t < 128 * 32; t += 256) {
            int r = t >> 5, c4 = (t & 31) * 4;
            float4 w = *(const float4*)(Wf + r * DIM + c4);
            uint2 pw = make_uint2(pack2bf(w.x, w.y), pack2bf(w.z, w.w));
            *(uint2*)(Wsh + r * WLD + c4) = pw;
        }
    } else {
        const u16* Wu = (const u16*)W;
        for (int t = tid; t < 128 * 16; t += 256) {
            int r = t >> 4, c8 = (t & 15) * 8;
            *(int4*)(Wsh + r * WLD + c8) = *(const int4*)(Wu + r * DIM + c8);
        }
    }

    const int wid = tid >> 6;
    const int lane = tid & 63;
    const int m_base = wid * 16;
    const int idx16 = lane & 15;
    const int koff = (lane >> 4) * 8;
    const int n = n0 + m_base + idx16;

    bf16x8 afrag[4];
    const u16* xu = (const u16*)in;
#pragma unroll
    for (int ks = 0; ks < 4; ++ks) {
        afrag[ks] = (n < N) ? *(const bf16x8*)(xu + (size_t)n * DIM + ks * 32 + koff)
                            : (bf16x8)0;
    }
    __syncthreads();  // Wsh ready

    f32x4 acc[8];
#pragma unroll
    for (int ct = 0; ct < 8; ++ct) acc[ct] = (f32x4){0.f, 0.f, 0.f, 0.f};

#pragma unroll
    for (int ct = 0; ct < 8; ++ct) {
#pragma unroll
        for (int ks = 0; ks < 4; ++ks) {
            bf16x8 bfrag = *(const bf16x8*)(Wsh + (ct * 16 + idx16) * WLD + ks * 32 + koff);
            acc[ct] = __builtin_amdgcn_mfma_f32_16x16x32_bf16(afrag[ks], bfrag, acc[ct], 0, 0, 0);
        }
    }

    const int drow = (lane >> 4) * 4;
#pragma unroll
    for (int ct = 0; ct < 8; ++ct) {
#pragma unroll
        for (int r = 0; r < 4; ++r) {
            int row = n0 + m_base + drow + r;
            if (row < N) h[(size_t)row * DIM + ct * 16 + idx16] = f2bf(acc[ct][r]);
        }
    }
}

// ---- fused CSR aggregate (best measured structure): one wave per dst.
// Self-loop lives IN elist (row len = deg+1, always >=1). 16 edges/iter, 4
// independent dwordx4 gathers in flight per lane; each instr covers 4 edges x
// 256B row = 1KB wave-wide, 100% line use. Clamped slots (w=0) re-read
// elist[last]'s row (L1 broadcast hit). Butterfly xor 16,32 merges quarters.
// NOTE (r1/r3/r9/r10 lessons): agg is per-CU miss-concurrency x LLC-latency
// bound (~3.1 TB/s beyond-L2); total line count is invariant under column
// chunking / XCD pinning / panel splits -- all three measured as regressions.
// Do not re-attempt locality schemes here. ----
template <bool RELU, bool OUT_BF16>
__global__ __launch_bounds__(256) void k_agg(const u16* __restrict__ h,
                                             const float* __restrict__ dis,
                                             const int* __restrict__ rowptr,
                                             const u32* __restrict__ elist,
                                             const void* __restrict__ bias,
                                             void* __restrict__ out, int N,
                                             const int* __restrict__ flagp) {
    const int lane = threadIdx.x & 63;
    const int d = blockIdx.x * 4 + (threadIdx.x >> 6);
    if (d >= N) return;
    const int flag = *flagp;
    const int q  = lane >> 4;        // quarter id -> edge residue class (mod 4)
    const int cb = (lane & 15) * 8;  // col base: 8 cols per lane

    const int start = rowptr[d];
    const int end   = rowptr[d + 1];
    const int last  = end - 1;       // end > start always (self-loop)
    const float dd  = dis[d];

    float acc[8];
#pragma unroll
    for (int k = 0; k < 8; ++k) acc[k] = 0.f;

    for (int j = start; j < end; j += 16) {
        const int i0 = j + q, i1 = i0 + 4, i2 = i0 + 8, i3 = i0 + 12;
        const u32 e0 = elist[i0 <= last ? i0 : last];
        const u32 e1 = elist[i1 <= last ? i1 : last];
        const u32 e2 = elist[i2 <= last ? i2 : last];
        const u32 e3 = elist[i3 <= last ? i3 : last];
        const float w0 = (i0 <= last) ? h16tof((u16)(e0 & 0xffff)) : 0.f;
        const float w1 = (i1 <= last) ? h16tof((u16)(e1 & 0xffff)) : 0.f;
        const float w2 = (i2 <= last) ? h16tof((u16)(e2 & 0xffff)) : 0.f;
        const float w3 = (i3 <= last) ? h16tof((u16)(e3 & 0xffff)) : 0.f;
        const int4 r0 = *(const int4*)(h + ((size_t)(e0 >> 16)) * DIM + cb);
        const int4 r1 = *(const int4*)(h + ((size_t)(e1 >> 16)) * DIM + cb);
        const int4 r2 = *(const int4*)(h + ((size_t)(e2 >> 16)) * DIM + cb);
        const int4 r3 = *(const int4*)(h + ((size_t)(e3 >> 16)) * DIM + cb);
        const u32 v0[4] = {(u32)r0.x, (u32)r0.y, (u32)r0.z, (u32)r0.w};
        const u32 v1[4] = {(u32)r1.x, (u32)r1.y, (u32)r1.z, (u32)r1.w};
        const u32 v2[4] = {(u32)r2.x, (u32)r2.y, (u32)r2.z, (u32)r2.w};
        const u32 v3[4] = {(u32)r3.x, (u32)r3.y, (u32)r3.z, (u32)r3.w};
#pragma unroll
        for (int k = 0; k < 4; ++k) {
            acc[2 * k]     = fmaf(bfbits2f((u16)(v0[k] & 0xffff)), w0, acc[2 * k]);
            acc[2 * k + 1] = fmaf(bfbits2f((u16)(v0[k] >> 16)),    w0, acc[2 * k + 1]);
        }
#pragma unroll
        for (int k = 0; k < 4; ++k) {
            acc[2 * k]     = fmaf(bfbits2f((u16)(v1[k] & 0xffff)), w1, acc[2 * k]);
            acc[2 * k + 1] = fmaf(bfbits2f((u16)(v1[k] >> 16)),    w1, acc[2 * k + 1]);
        }
#pragma unroll
        for (int k = 0; k < 4; ++k) {
            acc[2 * k]     = fmaf(bfbits2f((u16)(v2[k] & 0xffff)), w2, acc[2 * k]);
            acc[2 * k + 1] = fmaf(bfbits2f((u16)(v2[k] >> 16)),    w2, acc[2 * k + 1]);
        }
#pragma unroll
        for (int k = 0; k < 4; ++k) {
            acc[2 * k]     = fmaf(bfbits2f((u16)(v3[k] & 0xffff)), w3, acc[2 * k]);
            acc[2 * k + 1] = fmaf(bfbits2f((u16)(v3[k] >> 16)),    w3, acc[2 * k + 1]);
        }
    }

#pragma unroll
    for (int k = 0; k < 8; ++k) {
        acc[k] += __shfl_xor(acc[k], 16, 64);
        acc[k] += __shfl_xor(acc[k], 32, 64);
    }

    if (q != 0) return;  // epilogue on quarter 0: 16 lanes x 8 cols = 128 cols

    float res[8];
#pragma unroll
    for (int k = 0; k < 8; ++k) res[k] = acc[k] * dd;  // self-loop already summed
    if (flag) {
        const float* bf = (const float*)bias;
#pragma unroll
        for (int k = 0; k < 8; ++k) res[k] += bf[cb + k];
    } else {
        const u16* bu = (const u16*)bias;
#pragma unroll
        for (int k = 0; k < 8; ++k) res[k] += bfbits2f(bu[cb + k]);
    }
    if (RELU) {
#pragma unroll
        for (int k = 0; k < 8; ++k) res[k] = res[k] > 0.f ? res[k] : 0.01f * res[k];
    }
    if (OUT_BF16) {
        u32 pk[4];
#pragma unroll
        for (int k = 0; k < 4; ++k) pk[k] = pack2bf(res[2 * k], res[2 * k + 1]);
        *(int4*)((u16*)out + (size_t)d * DIM + cb) = make_int4(pk[0], pk[1], pk[2], pk[3]);
    } else {
        float* op = (float*)out + (size_t)d * DIM + cb;
        *(float4*)op       = make_float4(res[0], res[1], res[2], res[3]);
        *(float4*)(op + 4) = make_float4(res[4], res[5], res[6], res[7]);
    }
}

extern "C" void kernel_launch(void* const* d_in, const int* in_sizes, int n_in,
                              void* d_out, int out_size, void* d_ws, size_t ws_size,
                              hipStream_t stream) {
    const void* x  = d_in[0];             // f32 (probed; flag-adaptive)
    const int*  ei = (const int*)d_in[1];
    // d_in[2] = batch (unused in eval mode)
    const void* W1 = d_in[3];
    const void* b1 = d_in[4];
    const void* W2 = d_in[5];
    const void* b2 = d_in[6];

    const int N = in_sizes[0] / DIM;
    const int E = in_sizes[1] / 2;
    const int* src = ei;
    const int* dst = ei + E;
    const int chunk = (N + NCHUNK - 1) / NCHUNK;

    // ws layout (256B-aligned slices)
    char* ws = (char*)d_ws;
    size_t o = 0;
    int*   flagp    = (int*)(ws + o);   o += 256;
    float* dis      = (float*)(ws + o); o += (((size_t)N * 4 + 255) & ~(size_t)255);
    int*   counts   = (int*)(ws + o);   o += (((size_t)N * 4 + 255) & ~(size_t)255);
    int*   rowptr   = (int*)(ws + o);   o += (((size_t)(N + 1) * 4 + 255) & ~(size_t)255);
    u32*   pay      = (u32*)(ws + o);   o += (((size_t)N * 4 + 255) & ~(size_t)255);
    int*   chunksum = (int*)(ws + o);   o += 1024;
    int*   rank     = (int*)(ws + o);   o += (((size_t)E * 4 + 255) & ~(size_t)255);
    u32*   elist    = (u32*)(ws + o);   o += (((size_t)(E + N) * 4 + 255) & ~(size_t)255);
    u16*   h        = (u16*)(ws + o);   // N*128 bf16 = 12.8 MB

    const int gblk = (N + 63) / 64;
    const int cblk = (E + 1023) / 1024;
    const int fused_nb = 2 * (gblk > cblk ? gblk : cblk);
    const int fblk = (E + N + 255) / 256;
    const int ablk = (N + 3) / 4;

    // layer-1 activations (bf16, row-major) live in d_out's first 12.8 MB;
    // consumed by gemm2 BEFORE the final f32 aggregate overwrites d_out.
    u16* act = (u16*)d_out;

    hipMemsetAsync(counts, 0, (size_t)N * 4, stream);
    // fused: gemm1 (even blocks) || count+rank+probe (odd blocks)
    k_gemm_count<<<fused_nb, 256, 0, stream>>>(x, W1, h, N, dst, counts, rank, E,
                                               flagp, gblk, cblk);
    k_chunksum<<<NCHUNK, 256, 0, stream>>>(counts, chunksum, N, chunk);
    k_rowptr<<<NCHUNK, 256, 0, stream>>>(counts, chunksum, rowptr, dis, pay, N, chunk);
    k_fill<<<fblk, 256, 0, stream>>>(src, dst, rowptr, rank, pay, elist, E, N);

    // ---- layer 1 aggregate ----
    k_agg<true, true><<<ablk, 256, 0, stream>>>(h, dis, rowptr, elist, b1, act, N, flagp);

    // ---- layer 2 ----
    k_gemm<<<gblk, 256, 0, stream>>>(act, W2, h, N, flagp);
    k_agg<false, false><<<ablk, 256, 0, stream>>>(h, dis, rowptr, elist, b2, d_out, N, flagp);
}